// Round 4
// baseline (116.737 us; speedup 1.0000x reference)
//
#include <hip/hip_runtime.h>
#include <hip/hip_bf16.h>
#include <stdint.h>

// Problem constants (match reference setup_inputs)
#define BB   16
#define CC   64
#define LL   8192
#define OO   64
#define KK   3
#define TT   64        // positions per block tile
#define XSW  68        // xs fp32 row stride: 272B rows, 16B-aligned, bank step 4

typedef __attribute__((ext_vector_type(8))) short short8;     // 8 bf16 = 4 VGPRs (MFMA A/B frag)
typedef __attribute__((ext_vector_type(4))) float float4_t;   // MFMA C/D frag

__device__ __forceinline__ ushort f2bf(float f) {
    uint32_t u = __float_as_uint(f);
    return (ushort)((u + 0x7FFFu + ((u >> 16) & 1u)) >> 16);  // RNE
}

__device__ __forceinline__ uint32_t pk2(float lo, float hi) {
    float2 t; t.x = lo; t.y = hi;
    __hip_bfloat162 h = __float22bfloat162_rn(t);
    return *(uint32_t*)&h;
}

// Pre-kernel: weight [O][C][K] fp32 -> wt [O][K*64 + c] bf16 (row-major over ck=k*64+c)
__global__ void wt_prep(const float* __restrict__ w, ushort* __restrict__ wt) {
    int idx = blockIdx.x * 256 + threadIdx.x;
    if (idx < OO * CC * KK) {
        int f = idx / (CC * KK);
        int rem = idx - f * (CC * KK);
        int c = rem / KK;
        int k = rem - c * KK;
        wt[f * (KK * CC) + k * CC + c] = f2bf(w[idx]);
    }
}

// A = sampled (m = position), B = weight (n = filter).
// launch_bounds(256,6): 6 blocks/CU (24 waves/CU); VGPR must fit <=85.
__global__ __launch_bounds__(256, 6) void deform_main(
    const float* __restrict__ x, const float* __restrict__ offs,
    const ushort* __restrict__ wt, const float* __restrict__ bias,
    float* __restrict__ out) {

    // xs[pp][c] fp32, pp=0..71 <-> x_pad[ts-3+pp]; raw store xs[pp]=x[ts-4+pp].
    // GEMM reads pp in [3, 69] only. 19584 B.
    __shared__ float xs[72 * XSW];

    const int tid  = threadIdx.x;
    const int bb   = blockIdx.x >> 7;     // / (LL/TT = 128)
    const int tile = blockIdx.x & 127;
    const int ts   = tile * TT;
    const int lane = tid & 63;
    const int wv   = tid >> 6;

    // ---- Phase 1: x tile -> LDS, fp32, transposed, aligned float4 loads ----
    {
        const float* xb = x + (size_t)bb * (CC * LL);
        const int c     = wv * 16 + (lane >> 2);      // channel this lane stages
        const int fb    = lane & 3;                   // float4-index base within row
        const float* xrow = xb + (size_t)c * LL;
        #pragma unroll
        for (int i = 0; i < 5; i++) {
            int fi = fb + 4 * i;                      // 0..19, need 0..17
            int j0 = ts - 4 + 4 * fi;
            if (fi < 18 && j0 >= 0 && j0 <= LL - 4) { // skip OOB (edge tiles fix below)
                float4 v = *(const float4*)(xrow + j0);
                float* dst = &xs[(4 * fi) * XSW + c];
                dst[0 * XSW] = v.x; dst[1 * XSW] = v.y;
                dst[2 * XSW] = v.z; dst[3 * XSW] = v.w;
            }
        }
        // reflect fix-ups (only rows actually read): x_pad[0]=x[1], x_pad[8193]=x[8190]
        if (tile == 0   && tid < 64) xs[3 * XSW + tid]  = xb[(size_t)tid * LL + 1];
        if (tile == 127 && tid < 64) xs[68 * XSW + tid] = xb[(size_t)tid * LL + (LL - 2)];
    }

    // ---- Phase 1b: per-lane (U, w0, w1) for this lane's position n, all 3 taps ----
    const int lr = lane & 15;     // position within wave's 16-tile (A row), filter-within-tile (B row / C col)
    const int q  = lane >> 4;     // k-quad
    const int n  = wv * 16 + lr;  // this lane's position within the 64-tile
    int   ppk[KK];
    float w0k[KK], w1k[KK];
    {
        const float* ob = offs + ((size_t)bb * LL + ts + n) * KK;
        const float t0 = (float)(ts + n);
        #pragma unroll
        for (int k = 0; k < KK; k++) {
            float T = t0 + (float)k + ob[k];
            T = fmaxf(T, t0);
            T = fminf(T, t0 + 2.0f);
            int U = (int)floorf(T);
            if (U > LL) U = LL;                       // clip to Lp-2 = 8192
            float Uf = (float)U;
            ppk[k] = U - ts + 3;                      // xs row of lower neighbor
            w0k[k] = fmaxf(0.0f, 1.0f - fabsf(Uf - T));
            w1k[k] = fmaxf(0.0f, 1.0f - fabsf(Uf + 1.0f - T));
        }
    }
    __syncthreads();

    // ---- Phase 2: fused blend + GEMM. A-frag = sampled row (this lane's n), built in regs.
    // B-frags = weight rows f = ft*16+lr, straight from global wt (L2-resident, 12 KB).
    float4_t acc0 = {0.f, 0.f, 0.f, 0.f};
    float4_t acc1 = acc0, acc2 = acc0, acc3 = acc0;

    #pragma unroll
    for (int kk = 0; kk < 6; kk++) {
        const int k0 = kk * 32 + q * 8;               // ck index of this lane's 8 elems
        const int k  = k0 >> 6;                       // kernel tap
        const int c0 = k0 & 63;                       // channel offset (single tap)
        const int pp = ppk[k];
        const float w0 = w0k[k], w1 = w1k[k];
        const float4 r0a = *(const float4*)&xs[pp * XSW + c0];
        const float4 r0b = *(const float4*)&xs[pp * XSW + c0 + 4];
        const float4 r1a = *(const float4*)&xs[(pp + 1) * XSW + c0];
        const float4 r1b = *(const float4*)&xs[(pp + 1) * XSW + c0 + 4];
        union { short8 s; uint32_t u32[4]; } af;
        af.u32[0] = pk2(w0 * r0a.x + w1 * r1a.x, w0 * r0a.y + w1 * r1a.y);
        af.u32[1] = pk2(w0 * r0a.z + w1 * r1a.z, w0 * r0a.w + w1 * r1a.w);
        af.u32[2] = pk2(w0 * r0b.x + w1 * r1b.x, w0 * r0b.y + w1 * r1b.y);
        af.u32[3] = pk2(w0 * r0b.z + w1 * r1b.z, w0 * r0b.w + w1 * r1b.w);
        short8 b0 = *(const short8*)&wt[(0 * 16 + lr) * (KK * CC) + k0];
        short8 b1 = *(const short8*)&wt[(1 * 16 + lr) * (KK * CC) + k0];
        short8 b2 = *(const short8*)&wt[(2 * 16 + lr) * (KK * CC) + k0];
        short8 b3 = *(const short8*)&wt[(3 * 16 + lr) * (KK * CC) + k0];
        acc0 = __builtin_amdgcn_mfma_f32_16x16x32_bf16(af.s, b0, acc0, 0, 0, 0);
        acc1 = __builtin_amdgcn_mfma_f32_16x16x32_bf16(af.s, b1, acc1, 0, 0, 0);
        acc2 = __builtin_amdgcn_mfma_f32_16x16x32_bf16(af.s, b2, acc2, 0, 0, 0);
        acc3 = __builtin_amdgcn_mfma_f32_16x16x32_bf16(af.s, b3, acc3, 0, 0, 0);
    }

    // ---- Phase 3: epilogue. C/D: col = lane&15 = f-within-tile, row = q*4 + r = pos-within-tile.
    // Lane holds 4 CONSECUTIVE positions per f-tile -> float4 stores.
    const int pos0 = ts + wv * 16 + q * 4;
    float4_t accs[4] = {acc0, acc1, acc2, acc3};
    #pragma unroll
    for (int ft = 0; ft < 4; ft++) {
        const int f = ft * 16 + lr;
        const float bv = bias[f];
        float4 o;
        o.x = accs[ft][0] + bv;
        o.y = accs[ft][1] + bv;
        o.z = accs[ft][2] + bv;
        o.w = accs[ft][3] + bv;
        *(float4*)(out + ((size_t)bb * OO + f) * LL + pos0) = o;
    }
}

extern "C" void kernel_launch(void* const* d_in, const int* in_sizes, int n_in,
                              void* d_out, int out_size, void* d_ws, size_t ws_size,
                              hipStream_t stream) {
    const float* x    = (const float*)d_in[0];
    const float* offs = (const float*)d_in[1];
    const float* w    = (const float*)d_in[2];
    const float* bias = (const float*)d_in[3];
    float* out = (float*)d_out;
    ushort* wt = (ushort*)d_ws;   // 12288 bf16 = 24576 B scratch

    hipLaunchKernelGGL(wt_prep, dim3((OO * CC * KK + 255) / 256), dim3(256), 0, stream, w, wt);
    hipLaunchKernelGGL(deform_main, dim3(BB * (LL / TT)), dim3(256), 0, stream,
                       x, offs, wt, bias, out);
}

// Round 5
// 108.565 us; speedup vs baseline: 1.0753x; 1.0753x over previous
//
#include <hip/hip_runtime.h>
#include <hip/hip_bf16.h>
#include <stdint.h>

// Problem constants (match reference setup_inputs)
#define BB   16
#define CC   64
#define LL   8192
#define OO   64
#define KK   3
#define TT   64        // positions per tile
#define XSW  72        // xs bf16 row stride: 144 B rows (16B-aligned), bank step 36%32=4

typedef __attribute__((ext_vector_type(8))) short short8;     // 8 bf16 = 4 VGPRs (MFMA A/B frag)
typedef __attribute__((ext_vector_type(4))) float float4_t;   // MFMA C/D frag

__device__ __forceinline__ ushort f2bf(float f) {
    uint32_t u = __float_as_uint(f);
    return (ushort)((u + 0x7FFFu + ((u >> 16) & 1u)) >> 16);  // RNE
}
__device__ __forceinline__ float bf2f(ushort h) {
    return __uint_as_float(((uint32_t)h) << 16);
}
__device__ __forceinline__ uint32_t pk2(float lo, float hi) {
    float2 t; t.x = lo; t.y = hi;
    __hip_bfloat162 h = __float22bfloat162_rn(t);
    return *(uint32_t*)&h;
}

// Pre-kernel: weight [O][C][K] fp32 -> wt [O][K*64 + c] bf16 (row-major over ck=k*64+c)
__global__ void wt_prep(const float* __restrict__ w, ushort* __restrict__ wt) {
    int idx = blockIdx.x * 256 + threadIdx.x;
    if (idx < OO * CC * KK) {
        int f = idx / (CC * KK);
        int rem = idx - f * (CC * KK);
        int c = rem / KK;
        int k = rem - c * KK;
        wt[f * (KK * CC) + k * CC + c] = f2bf(w[idx]);
    }
}

// Persistent blocks: grid=768 (3/CU, all co-resident), 2-3 contiguous tiles each,
// double-buffered bf16 x tile in LDS, wt B-frags preloaded in registers.
// A = sampled (m = position), B = weight (n = filter).
__global__ __launch_bounds__(256, 3) void deform_main(
    const float* __restrict__ x, const float* __restrict__ offs,
    const ushort* __restrict__ wt, const float* __restrict__ bias,
    float* __restrict__ out) {

    // xs[buf][pp][c], pp=0..71 <-> x_pad[ts-3+pp]; GEMM reads pp in [3,69]. 2x10368 B.
    __shared__ ushort xs[2][72 * XSW];

    const int tid  = threadIdx.x;
    const int lane = tid & 63;
    const int wv   = tid >> 6;
    const int lr   = lane & 15;   // A row (position-in-16), B row (filter-in-16), C col
    const int q    = lane >> 4;   // k-quad
    const int g    = blockIdx.x;

    int t0, cnt;                  // contiguous tile chunk: 512 blocks x3, 256 blocks x2
    if (g < 512) { t0 = 3 * g; cnt = 3; }
    else         { t0 = 2 * g + 512; cnt = 2; }

    // ---- Once per block: preload all B-frags (24 x short8 = 96 VGPR) + bias ----
    short8 br[6][4];
    #pragma unroll
    for (int kk = 0; kk < 6; kk++)
        #pragma unroll
        for (int ft = 0; ft < 4; ft++)
            br[kk][ft] = *(const short8*)&wt[(ft * 16 + lr) * (KK * CC) + kk * 32 + q * 8];
    float bv[4];
    #pragma unroll
    for (int ft = 0; ft < 4; ft++) bv[ft] = bias[ft * 16 + lr];

    const int cch = wv * 16 + (lane >> 2);   // channel this lane stages
    const int fb  = lane & 3;                // float4-index base within row
    const int n   = wv * 16 + lr;            // this lane's position within the 64-tile

    float4 pv[5];                            // x prefetch regs (held across GEMM)
    float  po[3];                            // offsets prefetch
    int    ppk[3]; float w0k[3], w1k[3];     // current tile's interp state

    auto prefetch = [&](int tau) {           // issue global loads for tile tau
        int bb = tau >> 7, ts = (tau & 127) * TT;
        const float* xrow = x + ((size_t)bb * CC + cch) * LL;
        #pragma unroll
        for (int i = 0; i < 5; i++) {
            int fi = fb + 4 * i;             // 0..19, need 0..17
            int j0 = ts - 4 + 4 * fi;
            if (fi < 18 && j0 >= 0 && j0 <= LL - 4)
                pv[i] = *(const float4*)(xrow + j0);
        }
        const float* ob = offs + ((size_t)bb * LL + ts + n) * KK;
        #pragma unroll
        for (int k = 0; k < 3; k++) po[k] = ob[k];
    };

    auto stage = [&](int buf, int tau) {     // scatter pv -> LDS (transposed, bf16)
        int bb = tau >> 7, tile = tau & 127, ts = tile * TT;
        ushort* xsb = xs[buf];
        #pragma unroll
        for (int i = 0; i < 5; i++) {
            int fi = fb + 4 * i;
            int j0 = ts - 4 + 4 * fi;
            if (fi < 18 && j0 >= 0 && j0 <= LL - 4) {
                ushort* d = &xsb[(4 * fi) * XSW + cch];
                d[0 * XSW] = f2bf(pv[i].x); d[1 * XSW] = f2bf(pv[i].y);
                d[2 * XSW] = f2bf(pv[i].z); d[3 * XSW] = f2bf(pv[i].w);
            }
        }
        // reflect fix-ups: x_pad[0]=x[1] (row 3 of tile 0), x_pad[8193]=x[8190] (row 68 of tile 127)
        if (tile == 0   && tid < 64) xsb[ 3 * XSW + tid] = f2bf(x[((size_t)bb * CC + tid) * LL + 1]);
        if (tile == 127 && tid < 64) xsb[68 * XSW + tid] = f2bf(x[((size_t)bb * CC + tid) * LL + (LL - 2)]);
    };

    auto uw = [&](int tau) {                 // per-lane (pp, w0, w1) for all 3 taps
        int ts = (tau & 127) * TT;
        float t0f = (float)(ts + n);
        #pragma unroll
        for (int k = 0; k < 3; k++) {
            float T = t0f + (float)k + po[k];
            T = fmaxf(T, t0f);
            T = fminf(T, t0f + 2.0f);
            int U = (int)floorf(T);
            if (U > LL) U = LL;              // clip to Lp-2 = 8192
            float Uf = (float)U;
            ppk[k] = U - ts + 3;             // xs row of lower neighbor (in [3,68])
            w0k[k] = fmaxf(0.f, 1.f - fabsf(Uf - T));
            w1k[k] = fmaxf(0.f, 1.f - fabsf(Uf + 1.f - T));
        }
    };

    // ---- prologue: stage first tile ----
    prefetch(t0);
    stage(0, t0);
    uw(t0);
    __syncthreads();

    // ---- pipelined tile loop: 1 barrier/tile, no vmcnt ops inside the GEMM ----
    for (int it = 0; it < cnt; ++it) {
        const int tau = t0 + it;
        const int bb = tau >> 7, ts = (tau & 127) * TT;
        const bool more = (it + 1 < cnt);
        if (more) prefetch(tau + 1);         // loads in flight across the GEMM

        const ushort* xsb = xs[it & 1];
        float4_t acc0 = {0.f, 0.f, 0.f, 0.f};
        float4_t acc1 = acc0, acc2 = acc0, acc3 = acc0;

        #pragma unroll
        for (int kk = 0; kk < 6; kk++) {
            const int k0 = kk * 32 + q * 8;  // ck index of this lane's 8 elems
            const int k  = k0 >> 6;          // kernel tap
            const int c0 = k0 & 63;          // channel offset (single tap)
            const int pp = ppk[k];
            const float w0 = w0k[k], w1 = w1k[k];
            union { uint4 v; ushort u16[8]; } r0, r1;
            r0.v = *(const uint4*)&xsb[pp * XSW + c0];
            r1.v = *(const uint4*)&xsb[(pp + 1) * XSW + c0];
            union { short8 s; uint32_t u32[4]; } af;
            #pragma unroll
            for (int j = 0; j < 4; j++) {
                float v0 = w0 * bf2f(r0.u16[2 * j])     + w1 * bf2f(r1.u16[2 * j]);
                float v1 = w0 * bf2f(r0.u16[2 * j + 1]) + w1 * bf2f(r1.u16[2 * j + 1]);
                af.u32[j] = pk2(v0, v1);
            }
            acc0 = __builtin_amdgcn_mfma_f32_16x16x32_bf16(af.s, br[kk][0], acc0, 0, 0, 0);
            acc1 = __builtin_amdgcn_mfma_f32_16x16x32_bf16(af.s, br[kk][1], acc1, 0, 0, 0);
            acc2 = __builtin_amdgcn_mfma_f32_16x16x32_bf16(af.s, br[kk][2], acc2, 0, 0, 0);
            acc3 = __builtin_amdgcn_mfma_f32_16x16x32_bf16(af.s, br[kk][3], acc3, 0, 0, 0);
        }

        // epilogue: C/D col = lr = filter-in-tile, row = q*4+r = position -> float4 stores
        const int pos0 = ts + wv * 16 + q * 4;
        float4_t accs[4] = {acc0, acc1, acc2, acc3};
        #pragma unroll
        for (int ft = 0; ft < 4; ft++) {
            const int f = ft * 16 + lr;
            float4 o;
            o.x = accs[ft][0] + bv[ft];
            o.y = accs[ft][1] + bv[ft];
            o.z = accs[ft][2] + bv[ft];
            o.w = accs[ft][3] + bv[ft];
            *(float4*)(out + ((size_t)bb * OO + f) * LL + pos0) = o;
        }

        if (more) {
            stage((it + 1) & 1, tau + 1);    // other buffer: no WAR on current readers
            uw(tau + 1);
            __syncthreads();
        }
    }
}

extern "C" void kernel_launch(void* const* d_in, const int* in_sizes, int n_in,
                              void* d_out, int out_size, void* d_ws, size_t ws_size,
                              hipStream_t stream) {
    const float* x    = (const float*)d_in[0];
    const float* offs = (const float*)d_in[1];
    const float* w    = (const float*)d_in[2];
    const float* bias = (const float*)d_in[3];
    float* out = (float*)d_out;
    ushort* wt = (ushort*)d_ws;   // 12288 bf16 = 24576 B scratch

    hipLaunchKernelGGL(wt_prep, dim3((OO * CC * KK + 255) / 256), dim3(256), 0, stream, w, wt);
    hipLaunchKernelGGL(deform_main, dim3(768), dim3(256), 0, stream,
                       x, offs, wt, bias, out);
}